// Round 1
// 3226.191 us; speedup vs baseline: 1.0131x; 1.0131x over previous
//
#include <hip/hip_runtime.h>
#include <hip/hip_bf16.h>
#include <cstdint>
#include <cstddef>

#define DIM 4096
#define HIDDEN 11008
#define MTOK 8192   // B*S = 4*2048

typedef __bf16 bf16x8 __attribute__((ext_vector_type(8)));
typedef float floatx4 __attribute__((ext_vector_type(4)));

__device__ __forceinline__ unsigned short f2bf(float f) {
    union { float f; unsigned int u; } v; v.f = f;
    unsigned int r = v.u + 0x7FFFu + ((v.u >> 16) & 1u);
    return (unsigned short)(r >> 16);
}

__device__ __forceinline__ void gload16(const void* g, void* l) {
    __builtin_amdgcn_global_load_lds(
        (const __attribute__((address_space(1))) unsigned int*)g,
        (__attribute__((address_space(3))) unsigned int*)l,
        16, 0, 0);
}

__device__ __forceinline__ floatx4 mfma16(bf16x8 a, bf16x8 b, floatx4 c) {
    return __builtin_amdgcn_mfma_f32_16x16x32_bf16(a, b, c, 0, 0, 0);
}

// Raw barrier (no vmcnt drain) + IR/MIR code-motion fences.
#define FULL_BAR() do {                                   \
    asm volatile("" ::: "memory");                        \
    __builtin_amdgcn_s_barrier();                         \
    asm volatile("" ::: "memory");                        \
    __builtin_amdgcn_sched_barrier(0);                    \
} while (0)

// ---------------- conversion kernels ----------------

__global__ void cvt_f32_bf16(const float4* __restrict__ in, ushort4* __restrict__ out, int n4) {
    int i = blockIdx.x * 256 + threadIdx.x;
    if (i < n4) {
        float4 v = in[i];
        ushort4 o;
        o.x = f2bf(v.x); o.y = f2bf(v.y); o.z = f2bf(v.z); o.w = f2bf(v.w);
        out[i] = o;
    }
}

__global__ void cvt_i32_bf16(const int4* __restrict__ in, ushort4* __restrict__ out, int n4) {
    int i = blockIdx.x * 256 + threadIdx.x;
    if (i < n4) {
        int4 v = in[i];
        ushort4 o;
        o.x = f2bf((float)v.x); o.y = f2bf((float)v.y);
        o.z = f2bf((float)v.z); o.w = f2bf((float)v.w);
        out[i] = o;
    }
}

// Interleave gate/up into combined [2*HIDDEN][DIM]:
// combined row r: block b=r>>5; (r&16)==0 -> gate[b*16 + (r&15)], else up[b*16 + (r&15)].
__global__ void cvt_gateup(const int4* __restrict__ wg, const int4* __restrict__ wu,
                           ushort4* __restrict__ outc, int n4) {
    int i = blockIdx.x * 256 + threadIdx.x;
    if (i < n4) {
        const int rowc = i >> 10;               // DIM/4 = 1024 int4 per row
        const int col4 = i & 1023;
        const int srow = ((rowc >> 5) << 4) | (rowc & 15);
        const int4* __restrict__ src = (rowc & 16) ? wu : wg;
        int4 v = src[(size_t)srow * 1024 + col4];
        ushort4 o;
        o.x = f2bf((float)v.x); o.y = f2bf((float)v.y);
        o.z = f2bf((float)v.z); o.w = f2bf((float)v.w);
        outc[i] = o;
    }
}

// ---------------- GEMM1: 256x256 deep-pipelined, fused gate+up+SwiGLU ----------------
// A [MTOK,DIM] bf16; Bc [2*HIDDEN,DIM] bf16 (combined, 16-row interleave).
// Ring-4 LDS (BK=32), prefetch distance 3, vmcnt(8), swizzled reads.
__global__ __launch_bounds__(512, 2) void gemm_gateup(
    const unsigned short* __restrict__ A,
    const unsigned short* __restrict__ Bc,
    unsigned short* __restrict__ mid,
    const float* __restrict__ sgp, const float* __restrict__ sup)
{
    __shared__ __align__(16) unsigned short sA[4][256 * 32];
    __shared__ __align__(16) unsigned short sB[4][256 * 32];

    const int tid  = threadIdx.x;
    const int lane = tid & 63;
    const int wave = tid >> 6;      // 0..7
    const int wr   = wave >> 2;     // 0..1 : 128-row half
    const int wc   = wave & 3;      // 0..3 : 64-col quarter
    const int quad = lane >> 4;
    const int l16  = lane & 15;

    // bijective XCD swizzle (nwg = 2752 = 8*344)
    const int cpx = (int)gridDim.x >> 3;
    const int bid = blockIdx.x;
    const int swz = (bid & 7) * cpx + (bid >> 3);
    const int bm = swz & 31;        // 32 M-blocks
    const int bn = swz >> 5;        // 86 N-blocks

    const size_t m0 = (size_t)bm * 256;
    const size_t n0 = (size_t)bn * 256;

    // staging: thread t stages physical chunks t and t+512 of both A and B tiles.
    // physical chunk p -> (r=p>>2, c_phys=p&3); logical col chunk = c_phys ^ ((r>>1)&3)
    const int r0 = tid >> 2;                       // 0..127
    const int c0 = (tid & 3) ^ ((r0 >> 1) & 3);    // inverse-swizzled source chunk
    const unsigned short* gA0 = A  + (m0 + r0) * DIM + c0 * 8;
    const unsigned short* gA1 = gA0 + (size_t)128 * DIM;
    const unsigned short* gB0 = Bc + (n0 + r0) * DIM + c0 * 8;
    const unsigned short* gB1 = gB0 + (size_t)128 * DIM;

    // fragment reads: row = (block + l16), logical k-chunk = quad; swizzled col:
    const int co   = (quad ^ ((l16 >> 1) & 3)) * 8;
    const int aoff = (wr * 128 + l16) * 32 + co;
    const int boff = (wc * 64  + l16) * 32 + co;

    floatx4 acc[8][4];
    const floatx4 zero = {0.f, 0.f, 0.f, 0.f};
#pragma unroll
    for (int i = 0; i < 8; ++i)
#pragma unroll
        for (int j = 0; j < 4; ++j) acc[i][j] = zero;

    auto STAGE = [&](int kt) {
        const int s = kt & 3;
        const size_t ko = (size_t)kt * 32;
        gload16(gA0 + ko, &sA[s][tid * 8]);
        gload16(gA1 + ko, &sA[s][(512 + tid) * 8]);
        gload16(gB0 + ko, &sB[s][tid * 8]);
        gload16(gB1 + ko, &sB[s][(512 + tid) * 8]);
    };

    STAGE(0); STAGE(1); STAGE(2);
    asm volatile("s_waitcnt vmcnt(8)" ::: "memory");   // tile 0 landed (this wave)
    FULL_BAR();                                        // all waves' tile 0 landed

    const int KT = DIM / 32;   // 128
#pragma unroll 4
    for (int kt = 0; kt < KT; ++kt) {
        const unsigned short* pa = &sA[kt & 3][aoff];
        const unsigned short* pb = &sB[kt & 3][boff];
        bf16x8 a[4], b[4];
        // ---- phase A: m-half 0 ----
#pragma unroll
        for (int i = 0; i < 4; ++i) a[i] = *(const bf16x8*)(pa + i * 512);
#pragma unroll
        for (int j = 0; j < 4; ++j) b[j] = *(const bf16x8*)(pb + j * 512);
        if (kt + 3 < KT) STAGE(kt + 3);   // slot (kt-1)&3: all reads done before last BB2
        FULL_BAR();
        __builtin_amdgcn_s_setprio(1);
#pragma unroll
        for (int i = 0; i < 4; ++i)
#pragma unroll
            for (int j = 0; j < 4; ++j)
                acc[i][j] = mfma16(a[i], b[j], acc[i][j]);
        __builtin_amdgcn_s_setprio(0);
        FULL_BAR();
        // ---- phase B: m-half 1 (reuses b[]) ----
#pragma unroll
        for (int i = 0; i < 4; ++i) a[i] = *(const bf16x8*)(pa + 2048 + i * 512);
        asm volatile("s_waitcnt vmcnt(8)" ::: "memory");  // tile kt+1 fully landed
        FULL_BAR();
        __builtin_amdgcn_s_setprio(1);
#pragma unroll
        for (int i = 0; i < 4; ++i)
#pragma unroll
            for (int j = 0; j < 4; ++j)
                acc[4 + i][j] = mfma16(a[i], b[j], acc[4 + i][j]);
        __builtin_amdgcn_s_setprio(0);
        FULL_BAR();
    }

    // epilogue: j even = gate, j odd = up of the same 16 mid-columns
    const float s_g = *sgp;
    const float s_u = *sup;
    const size_t colb = (n0 >> 1) + (size_t)wc * 32 + l16;
#pragma unroll
    for (int i = 0; i < 8; ++i) {
        const size_t row = m0 + wr * 128 + i * 16 + quad * 4;
#pragma unroll
        for (int jj = 0; jj < 2; ++jj) {
            const size_t col = colb + jj * 16;
#pragma unroll
            for (int r = 0; r < 4; ++r) {
                float g = acc[i][2 * jj][r] * s_g;
                float u = acc[i][2 * jj + 1][r] * s_u;
                float v = g * u / (1.0f + __expf(-g));
                mid[(row + r) * HIDDEN + col] = f2bf(v);
            }
        }
    }
}

// ---------------- GEMM2: down projection, same pipeline ----------------
// A = mid [MTOK,HIDDEN] bf16; B = w_down [DIM,HIDDEN] bf16 (NT). fp32 out.
__global__ __launch_bounds__(512, 2) void gemm_down(
    const unsigned short* __restrict__ A,
    const unsigned short* __restrict__ B,
    float* __restrict__ out,
    const float* __restrict__ sdp)
{
    __shared__ __align__(16) unsigned short sA[4][256 * 32];
    __shared__ __align__(16) unsigned short sB[4][256 * 32];

    const int tid  = threadIdx.x;
    const int lane = tid & 63;
    const int wave = tid >> 6;
    const int wr   = wave >> 2;
    const int wc   = wave & 3;
    const int quad = lane >> 4;
    const int l16  = lane & 15;

    // bijective XCD swizzle (nwg = 512 = 8*64)
    const int cpx = (int)gridDim.x >> 3;
    const int bid = blockIdx.x;
    const int swz = (bid & 7) * cpx + (bid >> 3);
    const int bm = swz & 31;        // 32 M-blocks
    const int bn = swz >> 5;        // 16 N-blocks

    const size_t m0 = (size_t)bm * 256;
    const size_t n0 = (size_t)bn * 256;

    const int r0 = tid >> 2;
    const int c0 = (tid & 3) ^ ((r0 >> 1) & 3);
    const unsigned short* gA0 = A + (m0 + r0) * HIDDEN + c0 * 8;
    const unsigned short* gA1 = gA0 + (size_t)128 * HIDDEN;
    const unsigned short* gB0 = B + (n0 + r0) * HIDDEN + c0 * 8;
    const unsigned short* gB1 = gB0 + (size_t)128 * HIDDEN;

    const int co   = (quad ^ ((l16 >> 1) & 3)) * 8;
    const int aoff = (wr * 128 + l16) * 32 + co;
    const int boff = (wc * 64  + l16) * 32 + co;

    floatx4 acc[8][4];
    const floatx4 zero = {0.f, 0.f, 0.f, 0.f};
#pragma unroll
    for (int i = 0; i < 8; ++i)
#pragma unroll
        for (int j = 0; j < 4; ++j) acc[i][j] = zero;

    auto STAGE = [&](int kt) {
        const int s = kt & 3;
        const size_t ko = (size_t)kt * 32;
        gload16(gA0 + ko, &sA[s][tid * 8]);
        gload16(gA1 + ko, &sA[s][(512 + tid) * 8]);
        gload16(gB0 + ko, &sB[s][tid * 8]);
        gload16(gB1 + ko, &sB[s][(512 + tid) * 8]);
    };

    STAGE(0); STAGE(1); STAGE(2);
    asm volatile("s_waitcnt vmcnt(8)" ::: "memory");
    FULL_BAR();

    const int KT = HIDDEN / 32;   // 344
#pragma unroll 4
    for (int kt = 0; kt < KT; ++kt) {
        const unsigned short* pa = &sA[kt & 3][aoff];
        const unsigned short* pb = &sB[kt & 3][boff];
        bf16x8 a[4], b[4];
#pragma unroll
        for (int i = 0; i < 4; ++i) a[i] = *(const bf16x8*)(pa + i * 512);
#pragma unroll
        for (int j = 0; j < 4; ++j) b[j] = *(const bf16x8*)(pb + j * 512);
        if (kt + 3 < KT) STAGE(kt + 3);
        FULL_BAR();
        __builtin_amdgcn_s_setprio(1);
#pragma unroll
        for (int i = 0; i < 4; ++i)
#pragma unroll
            for (int j = 0; j < 4; ++j)
                acc[i][j] = mfma16(a[i], b[j], acc[i][j]);
        __builtin_amdgcn_s_setprio(0);
        FULL_BAR();
#pragma unroll
        for (int i = 0; i < 4; ++i) a[i] = *(const bf16x8*)(pa + 2048 + i * 512);
        asm volatile("s_waitcnt vmcnt(8)" ::: "memory");
        FULL_BAR();
        __builtin_amdgcn_s_setprio(1);
#pragma unroll
        for (int i = 0; i < 4; ++i)
#pragma unroll
            for (int j = 0; j < 4; ++j)
                acc[4 + i][j] = mfma16(a[i], b[j], acc[4 + i][j]);
        __builtin_amdgcn_s_setprio(0);
        FULL_BAR();
    }

    const float s_d = *sdp;
#pragma unroll
    for (int i = 0; i < 8; ++i) {
        const size_t row = m0 + wr * 128 + i * 16 + quad * 4;
#pragma unroll
        for (int j = 0; j < 4; ++j) {
            const size_t col = n0 + wc * 64 + j * 16 + l16;
#pragma unroll
            for (int r = 0; r < 4; ++r)
                out[(row + r) * DIM + col] = acc[i][j][r] * s_d;
        }
    }
}

// ---------------- launch ----------------

extern "C" void kernel_launch(void* const* d_in, const int* in_sizes, int n_in,
                              void* d_out, int out_size, void* d_ws, size_t ws_size,
                              hipStream_t stream) {
    const float* x  = (const float*)d_in[0];
    const int*   wg = (const int*)d_in[1];
    const int*   wu = (const int*)d_in[2];
    const int*   wd = (const int*)d_in[3];
    const float* sg = (const float*)d_in[4];
    const float* su = (const float*)d_in[5];
    const float* sd = (const float*)d_in[6];
    float* out = (float*)d_out;

    // workspace carve-up (all bf16 as ushort). Total = 517,996,544 bytes (unchanged).
    unsigned short* xb   = (unsigned short*)d_ws;
    unsigned short* wcb  = xb  + (size_t)MTOK * DIM;          // combined gate/up [22016][4096]
    unsigned short* wdb  = wcb + (size_t)2 * HIDDEN * DIM;
    unsigned short* midb = wdb + (size_t)DIM * HIDDEN;

    // 1) conversions
    {
        int n4 = MTOK * DIM / 4;
        cvt_f32_bf16<<<dim3((n4 + 255) / 256), 256, 0, stream>>>((const float4*)x, (ushort4*)xb, n4);
    }
    {
        int n4 = 2 * HIDDEN * DIM / 4;
        cvt_gateup<<<dim3((n4 + 255) / 256), 256, 0, stream>>>(
            (const int4*)wg, (const int4*)wu, (ushort4*)wcb, n4);
    }
    {
        int n4 = DIM * HIDDEN / 4;
        cvt_i32_bf16<<<dim3((n4 + 255) / 256), 256, 0, stream>>>((const int4*)wd, (ushort4*)wdb, n4);
    }

    // 2) fused gate+up GEMM + SwiGLU -> mid (bf16)
    gemm_gateup<<<dim3((MTOK / 256) * (2 * HIDDEN / 256)), 512, 0, stream>>>(xb, wcb, midb, sg, su);

    // 3) down GEMM -> out (fp32)
    gemm_down<<<dim3((MTOK / 256) * (DIM / 256)), 512, 0, stream>>>(midb, wdb, out, sd);
}

// Round 2
// 2819.020 us; speedup vs baseline: 1.1595x; 1.1444x over previous
//
#include <hip/hip_runtime.h>
#include <hip/hip_bf16.h>
#include <cstdint>
#include <cstddef>

#define DIM 4096
#define HIDDEN 11008
#define MTOK 8192   // B*S = 4*2048

typedef __bf16 bf16x8 __attribute__((ext_vector_type(8)));
typedef float floatx4 __attribute__((ext_vector_type(4)));

__device__ __forceinline__ unsigned short f2bf(float f) {
    union { float f; unsigned int u; } v; v.f = f;
    unsigned int r = v.u + 0x7FFFu + ((v.u >> 16) & 1u);
    return (unsigned short)(r >> 16);
}

__device__ __forceinline__ void gload16(const void* g, void* l) {
    __builtin_amdgcn_global_load_lds(
        (const __attribute__((address_space(1))) unsigned int*)g,
        (__attribute__((address_space(3))) unsigned int*)l,
        16, 0, 0);
}

__device__ __forceinline__ floatx4 mfma16(bf16x8 a, bf16x8 b, floatx4 c) {
    return __builtin_amdgcn_mfma_f32_16x16x32_bf16(a, b, c, 0, 0, 0);
}

// ---------------- conversion kernels ----------------

__global__ void cvt_f32_bf16(const float4* __restrict__ in, ushort4* __restrict__ out, int n4) {
    int i = blockIdx.x * 256 + threadIdx.x;
    if (i < n4) {
        float4 v = in[i];
        ushort4 o;
        o.x = f2bf(v.x); o.y = f2bf(v.y); o.z = f2bf(v.z); o.w = f2bf(v.w);
        out[i] = o;
    }
}

__global__ void cvt_i32_bf16(const int4* __restrict__ in, ushort4* __restrict__ out, int n4) {
    int i = blockIdx.x * 256 + threadIdx.x;
    if (i < n4) {
        int4 v = in[i];
        ushort4 o;
        o.x = f2bf((float)v.x); o.y = f2bf((float)v.y);
        o.z = f2bf((float)v.z); o.w = f2bf((float)v.w);
        out[i] = o;
    }
}

// Interleave gate/up into combined [2*HIDDEN][DIM]:
// combined row r: block b=r>>5; (r&16)==0 -> gate[b*16 + (r&15)], else up[b*16 + (r&15)].
__global__ void cvt_gateup(const int4* __restrict__ wg, const int4* __restrict__ wu,
                           ushort4* __restrict__ outc, int n4) {
    int i = blockIdx.x * 256 + threadIdx.x;
    if (i < n4) {
        const int rowc = i >> 10;               // DIM/4 = 1024 int4 per row
        const int col4 = i & 1023;
        const int srow = ((rowc >> 5) << 4) | (rowc & 15);
        const int4* __restrict__ src = (rowc & 16) ? wu : wg;
        int4 v = src[(size_t)srow * 1024 + col4];
        ushort4 o;
        o.x = f2bf((float)v.x); o.y = f2bf((float)v.y);
        o.z = f2bf((float)v.z); o.w = f2bf((float)v.w);
        outc[i] = o;
    }
}

// ---------------- GEMM1: 256x256, single-segment pipelined, fused gate+up+SwiGLU ----------------
// A [MTOK,DIM] bf16; Bc [2*HIDDEN,DIM] bf16 (combined, 16-row interleave).
// Ring-4 LDS (BK=32), prefetch distance 3, ONE barrier + ONE counted vmcnt per K-step.
__global__ __launch_bounds__(512, 2) void gemm_gateup(
    const unsigned short* __restrict__ A,
    const unsigned short* __restrict__ Bc,
    unsigned short* __restrict__ mid,
    const float* __restrict__ sgp, const float* __restrict__ sup)
{
    __shared__ __align__(16) unsigned short sA[4][256 * 32];
    __shared__ __align__(16) unsigned short sB[4][256 * 32];

    const int tid  = threadIdx.x;
    const int lane = tid & 63;
    const int wave = tid >> 6;      // 0..7
    const int wr   = wave >> 2;     // 0..1 : 128-row half
    const int wc   = wave & 3;      // 0..3 : 64-col quarter
    const int quad = lane >> 4;
    const int l16  = lane & 15;

    // bijective XCD swizzle (nwg = 2752 = 8*344)
    const int cpx = (int)gridDim.x >> 3;
    const int bid = blockIdx.x;
    const int swz = (bid & 7) * cpx + (bid >> 3);
    const int bm = swz & 31;        // 32 M-blocks
    const int bn = swz >> 5;        // 86 N-blocks

    const size_t m0 = (size_t)bm * 256;
    const size_t n0 = (size_t)bn * 256;

    // staging: thread t stages physical chunks t and t+512 of both A and B tiles.
    // physical chunk p -> (r=p>>2, c_phys=p&3); logical col chunk = c_phys ^ ((r>>1)&3)
    const int r0 = tid >> 2;                       // 0..127
    const int c0 = (tid & 3) ^ ((r0 >> 1) & 3);    // inverse-swizzled source chunk
    const unsigned short* gA0 = A  + (m0 + r0) * DIM + c0 * 8;
    const unsigned short* gA1 = gA0 + (size_t)128 * DIM;
    const unsigned short* gB0 = Bc + (n0 + r0) * DIM + c0 * 8;
    const unsigned short* gB1 = gB0 + (size_t)128 * DIM;

    // fragment reads: row = (block + l16), logical k-chunk = quad; swizzled col:
    const int co   = (quad ^ ((l16 >> 1) & 3)) * 8;
    const int aoff = (wr * 128 + l16) * 32 + co;
    const int boff = (wc * 64  + l16) * 32 + co;

    floatx4 acc[8][4];
    const floatx4 zero = {0.f, 0.f, 0.f, 0.f};
#pragma unroll
    for (int i = 0; i < 8; ++i)
#pragma unroll
        for (int j = 0; j < 4; ++j) acc[i][j] = zero;

    auto STAGE = [&](int kt) {
        const int s = kt & 3;
        const size_t ko = (size_t)kt * 32;
        gload16(gA0 + ko, &sA[s][tid * 8]);
        gload16(gA1 + ko, &sA[s][(512 + tid) * 8]);
        gload16(gB0 + ko, &sB[s][tid * 8]);
        gload16(gB1 + ko, &sB[s][(512 + tid) * 8]);
    };

    STAGE(0); STAGE(1); STAGE(2);
    asm volatile("s_waitcnt vmcnt(8)" ::: "memory");   // tile 0 landed (this wave)
    __builtin_amdgcn_s_barrier();                      // all waves' tile 0 landed
    __builtin_amdgcn_sched_barrier(0);

    const int KT = DIM / 32;   // 128
#pragma unroll 4
    for (int kt = 0; kt < KT; ++kt) {
        const unsigned short* pa = &sA[kt & 3][aoff];
        const unsigned short* pb = &sB[kt & 3][boff];
        bf16x8 a[8], b[4];
#pragma unroll
        for (int i = 0; i < 4; ++i) a[i]     = *(const bf16x8*)(pa + i * 512);
#pragma unroll
        for (int j = 0; j < 4; ++j) b[j]     = *(const bf16x8*)(pb + j * 512);
#pragma unroll
        for (int i = 0; i < 4; ++i) a[4 + i] = *(const bf16x8*)(pa + 2048 + i * 512);
        if (kt + 3 < KT) STAGE(kt + 3);   // slot (kt-1)&3: its readers finished before BAR(kt-1)
        // one big segment: compiler interleaves ds_reads / gloads / MFMAs freely
#pragma unroll
        for (int i = 0; i < 8; ++i)
#pragma unroll
            for (int j = 0; j < 4; ++j)
                acc[i][j] = mfma16(a[i], b[j], acc[i][j]);
        if (kt < KT - 3) { asm volatile("s_waitcnt vmcnt(8)" ::: "memory"); } // tile kt+1 landed
        else             { asm volatile("s_waitcnt vmcnt(0)" ::: "memory"); } // tail drain
        __builtin_amdgcn_s_barrier();
        __builtin_amdgcn_sched_barrier(0);
    }

    // epilogue: j even = gate, j odd = up of the same 16 mid-columns
    const float s_g = *sgp;
    const float s_u = *sup;
    const size_t colb = (n0 >> 1) + (size_t)wc * 32 + l16;
#pragma unroll
    for (int i = 0; i < 8; ++i) {
        const size_t row = m0 + wr * 128 + i * 16 + quad * 4;
#pragma unroll
        for (int jj = 0; jj < 2; ++jj) {
            const size_t col = colb + jj * 16;
#pragma unroll
            for (int r = 0; r < 4; ++r) {
                float g = acc[i][2 * jj][r] * s_g;
                float u = acc[i][2 * jj + 1][r] * s_u;
                float v = g * u / (1.0f + __expf(-g));
                mid[(row + r) * HIDDEN + col] = f2bf(v);
            }
        }
    }
}

// ---------------- GEMM2: down projection, same pipeline ----------------
// A = mid [MTOK,HIDDEN] bf16; B = w_down [DIM,HIDDEN] bf16 (NT). fp32 out.
__global__ __launch_bounds__(512, 2) void gemm_down(
    const unsigned short* __restrict__ A,
    const unsigned short* __restrict__ B,
    float* __restrict__ out,
    const float* __restrict__ sdp)
{
    __shared__ __align__(16) unsigned short sA[4][256 * 32];
    __shared__ __align__(16) unsigned short sB[4][256 * 32];

    const int tid  = threadIdx.x;
    const int lane = tid & 63;
    const int wave = tid >> 6;
    const int wr   = wave >> 2;
    const int wc   = wave & 3;
    const int quad = lane >> 4;
    const int l16  = lane & 15;

    // bijective XCD swizzle (nwg = 512 = 8*64)
    const int cpx = (int)gridDim.x >> 3;
    const int bid = blockIdx.x;
    const int swz = (bid & 7) * cpx + (bid >> 3);
    const int bm = swz & 31;        // 32 M-blocks
    const int bn = swz >> 5;        // 16 N-blocks

    const size_t m0 = (size_t)bm * 256;
    const size_t n0 = (size_t)bn * 256;

    const int r0 = tid >> 2;
    const int c0 = (tid & 3) ^ ((r0 >> 1) & 3);
    const unsigned short* gA0 = A + (m0 + r0) * HIDDEN + c0 * 8;
    const unsigned short* gA1 = gA0 + (size_t)128 * HIDDEN;
    const unsigned short* gB0 = B + (n0 + r0) * HIDDEN + c0 * 8;
    const unsigned short* gB1 = gB0 + (size_t)128 * HIDDEN;

    const int co   = (quad ^ ((l16 >> 1) & 3)) * 8;
    const int aoff = (wr * 128 + l16) * 32 + co;
    const int boff = (wc * 64  + l16) * 32 + co;

    floatx4 acc[8][4];
    const floatx4 zero = {0.f, 0.f, 0.f, 0.f};
#pragma unroll
    for (int i = 0; i < 8; ++i)
#pragma unroll
        for (int j = 0; j < 4; ++j) acc[i][j] = zero;

    auto STAGE = [&](int kt) {
        const int s = kt & 3;
        const size_t ko = (size_t)kt * 32;
        gload16(gA0 + ko, &sA[s][tid * 8]);
        gload16(gA1 + ko, &sA[s][(512 + tid) * 8]);
        gload16(gB0 + ko, &sB[s][tid * 8]);
        gload16(gB1 + ko, &sB[s][(512 + tid) * 8]);
    };

    STAGE(0); STAGE(1); STAGE(2);
    asm volatile("s_waitcnt vmcnt(8)" ::: "memory");
    __builtin_amdgcn_s_barrier();
    __builtin_amdgcn_sched_barrier(0);

    const int KT = HIDDEN / 32;   // 344
#pragma unroll 4
    for (int kt = 0; kt < KT; ++kt) {
        const unsigned short* pa = &sA[kt & 3][aoff];
        const unsigned short* pb = &sB[kt & 3][boff];
        bf16x8 a[8], b[4];
#pragma unroll
        for (int i = 0; i < 4; ++i) a[i]     = *(const bf16x8*)(pa + i * 512);
#pragma unroll
        for (int j = 0; j < 4; ++j) b[j]     = *(const bf16x8*)(pb + j * 512);
#pragma unroll
        for (int i = 0; i < 4; ++i) a[4 + i] = *(const bf16x8*)(pa + 2048 + i * 512);
        if (kt + 3 < KT) STAGE(kt + 3);
#pragma unroll
        for (int i = 0; i < 8; ++i)
#pragma unroll
            for (int j = 0; j < 4; ++j)
                acc[i][j] = mfma16(a[i], b[j], acc[i][j]);
        if (kt < KT - 3) { asm volatile("s_waitcnt vmcnt(8)" ::: "memory"); }
        else             { asm volatile("s_waitcnt vmcnt(0)" ::: "memory"); }
        __builtin_amdgcn_s_barrier();
        __builtin_amdgcn_sched_barrier(0);
    }

    const float s_d = *sdp;
#pragma unroll
    for (int i = 0; i < 8; ++i) {
        const size_t row = m0 + wr * 128 + i * 16 + quad * 4;
#pragma unroll
        for (int j = 0; j < 4; ++j) {
            const size_t col = n0 + wc * 64 + j * 16 + l16;
#pragma unroll
            for (int r = 0; r < 4; ++r)
                out[(row + r) * DIM + col] = acc[i][j][r] * s_d;
        }
    }
}

// ---------------- launch ----------------

extern "C" void kernel_launch(void* const* d_in, const int* in_sizes, int n_in,
                              void* d_out, int out_size, void* d_ws, size_t ws_size,
                              hipStream_t stream) {
    const float* x  = (const float*)d_in[0];
    const int*   wg = (const int*)d_in[1];
    const int*   wu = (const int*)d_in[2];
    const int*   wd = (const int*)d_in[3];
    const float* sg = (const float*)d_in[4];
    const float* su = (const float*)d_in[5];
    const float* sd = (const float*)d_in[6];
    float* out = (float*)d_out;

    // workspace carve-up (all bf16 as ushort). Total = 517,996,544 bytes (unchanged).
    unsigned short* xb   = (unsigned short*)d_ws;
    unsigned short* wcb  = xb  + (size_t)MTOK * DIM;          // combined gate/up [22016][4096]
    unsigned short* wdb  = wcb + (size_t)2 * HIDDEN * DIM;
    unsigned short* midb = wdb + (size_t)DIM * HIDDEN;

    // 1) conversions
    {
        int n4 = MTOK * DIM / 4;
        cvt_f32_bf16<<<dim3((n4 + 255) / 256), 256, 0, stream>>>((const float4*)x, (ushort4*)xb, n4);
    }
    {
        int n4 = 2 * HIDDEN * DIM / 4;
        cvt_gateup<<<dim3((n4 + 255) / 256), 256, 0, stream>>>(
            (const int4*)wg, (const int4*)wu, (ushort4*)wcb, n4);
    }
    {
        int n4 = DIM * HIDDEN / 4;
        cvt_i32_bf16<<<dim3((n4 + 255) / 256), 256, 0, stream>>>((const int4*)wd, (ushort4*)wdb, n4);
    }

    // 2) fused gate+up GEMM + SwiGLU -> mid (bf16)
    gemm_gateup<<<dim3((MTOK / 256) * (2 * HIDDEN / 256)), 512, 0, stream>>>(xb, wcb, midb, sg, su);

    // 3) down GEMM -> out (fp32)
    gemm_down<<<dim3((MTOK / 256) * (DIM / 256)), 512, 0, stream>>>(midb, wdb, out, sd);
}